// Round 17
// baseline (92.060 us; speedup 1.0000x reference)
//
#include <hip/hip_runtime.h>
#include <math.h>

#define NN 1536
#define FF 32
#define HH 64
#define EE (NN*(NN-1)/2)
#define EBLK 1248          // 1248 blocks * 4 waves * 2 chunks = 9984 >= 9972
#define BN_EPS 1e-5f
#define SLOPE 0.01f

typedef _Float16 v8h   __attribute__((ext_vector_type(8)));
typedef __fp16   v2hf  __attribute__((ext_vector_type(2)));
typedef float    f32x4 __attribute__((ext_vector_type(4)));

union V8H { v8h v; v2hf h2[4]; float4 f4; };

__device__ __forceinline__ float lrelu_f(float v){ return v >= 0.f ? v : SLOPE*v; }

// ---------------------------------------------------------------------------
// Node pipeline (r12 structure: partials flow through kernel boundaries).
__global__ __launch_bounds__(256) void k_first(
    const float* __restrict__ nf, float* __restrict__ H,
    const float* __restrict__ pw2, const float* __restrict__ pw3,
    const float* __restrict__ pw4,
    _Float16* __restrict__ pwf) {
  int bid = blockIdx.x, tid = threadIdx.x;
  if (bid >= 96) {
    int i = (bid - 96)*256 + tid;     // 9216 elems over 36 blocks
    if (i < 8192) {
      int mat = i >> 12, r = i & 4095;
      int k = r >> 6, cout = r & 63;
      int m = cout >> 4, cc = cout & 15;
      int q, g, b;
      if (mat == 0) { q = k >> 5; g = (k >> 3) & 3; b = k & 7; }
      else { int mF = k >> 4; g = (k >> 2) & 3; int rr = k & 3; q = mF >> 1; b = ((mF & 1) << 2) | rr; }
      const float* W = mat ? pw3 : pw2;
      pwf[mat*4096 + ((q*4 + m)*64 + (g*16 + cc))*8 + b] = (_Float16)W[r];
    } else if (i < 9216) {
      int e = i - 8192;
      int fi = e >> 9, rem = e & 511;
      int lane = rem >> 3, b = rem & 7;
      int g = lane >> 4, r = lane & 15;
      int q = b >> 2, j = b & 3;
      float val = (r == 0) ? pw4[fi*32 + 16*q + 4*g + j] : 0.f;
      pwf[i] = (_Float16)val;
    }
    return;
  }
  __shared__ float part[8][32];
  int c = tid & 31, y = tid >> 5;
  float s = nf[(bid*16 + y)*32 + c] + nf[(bid*16 + y + 8)*32 + c];
  part[y][c] = s;
  __syncthreads();
  if (y == 0) {
    float S = 0.f;
#pragma unroll
    for (int r = 0; r < 8; ++r) S += part[r][c];
    H[bid*64 + c] = S;
  }
}

__global__ __launch_bounds__(256) void k_bn(
    const float* __restrict__ z, const float* __restrict__ P,
    const float* __restrict__ gg, const float* __restrict__ be,
    float* __restrict__ hbuf, float* __restrict__ H) {
  __shared__ float sums[2][128];
  __shared__ float scl[64], sft[64];
  __shared__ float part[4][64];
  int tid = threadIdx.x, bid = blockIdx.x;
  {
    int c2 = tid & 127, half = tid >> 7;
    float S0 = 0.f, S1 = 0.f;
    int j0 = half*48;
    for (int j = j0; j < j0 + 48; j += 2) { S0 += P[j*128 + c2]; S1 += P[(j+1)*128 + c2]; }
    sums[half][c2] = S0 + S1;
  }
  __syncthreads();
  if (tid < 64) {
    float S = sums[0][tid] + sums[1][tid];
    float Q = sums[0][64 + tid] + sums[1][64 + tid];
    float m  = S * (1.f/NN);
    float iv = rsqrtf(Q * (1.f/NN) - m*m + BN_EPS);
    float sc = iv * gg[tid];
    scl[tid] = sc;
    sft[tid] = be[tid] - m*sc;
  }
  __syncthreads();
  int c = tid & 63, y = tid >> 6;
  float sc = scl[c], sh = sft[c];
  float hs = 0.f;
#pragma unroll
  for (int i = 0; i < 4; ++i) {
    int rr = y + 4*i;
    float h = lrelu_f(z[(bid*16 + rr)*64 + c]*sc + sh);
    hbuf[(bid*16 + rr)*64 + c] = h;
    hs += h;
  }
  part[y][c] = hs;
  __syncthreads();
  if (y == 0)
    H[bid*64 + c] = part[0][c] + part[1][c] + part[2][c] + part[3][c];
}

template<int DIN>
__global__ __launch_bounds__(512) void k_mmp(
    const float* __restrict__ hb, const float* __restrict__ H,
    const float* __restrict__ eps_p,
    const float* __restrict__ W1, const float* __restrict__ b1,
    const float* __restrict__ W2, const float* __restrict__ b2,
    float* __restrict__ zout, float* __restrict__ P) {
  __shared__ float W1s[DIN*64];
  __shared__ float W2s[4096];
  __shared__ float red[8][64];
  __shared__ float pf[64];
  __shared__ float hh[16][DIN];
  __shared__ float uls[16*DIN];
  __shared__ float t1s[16][64];
  __shared__ float pp[8][64], pq[8][64];
  int tid = threadIdx.x, bid = blockIdx.x;
  int c = tid & 63, y = tid >> 6;
  for (int i = tid; i < DIN*64; i += 512) W1s[i] = W1[i];
  for (int i = tid; i < 4096; i += 512)   W2s[i] = W2[i];

  {
    float s = 0.f;
    if (c < DIN) for (int j = y; j < bid; j += 8) s += H[j*64 + c];
    red[y][c] = s;
  }
  if (c < DIN) {
    hh[y][c]     = hb[(bid*16 + y)*DIN + c];
    hh[y + 8][c] = hb[(bid*16 + y + 8)*DIN + c];
  }
  __syncthreads();
  if (y == 0 && c < DIN) {
    float S = 0.f;
#pragma unroll
    for (int r = 0; r < 8; ++r) S += red[r][c];
    pf[c] = S;
  }
  __syncthreads();

  float e1 = 1.f + eps_p[0];
  if (c < DIN) {
    for (int rr = y; rr < 16; rr += 8) {
      float run = pf[c];
      for (int r2 = 0; r2 < rr; ++r2) run += hh[r2][c];
      uls[rr*DIN + c] = e1*hh[rr][c] + run;
    }
  }
  __syncthreads();

  float a0 = b1[c], a1 = a0;
  for (int k = 0; k < DIN; ++k) {
    float w = W1s[k*64 + c];
    a0 = fmaf(uls[y*DIN + k],       w, a0);
    a1 = fmaf(uls[(y + 8)*DIN + k], w, a1);
  }
  t1s[y][c]     = fmaxf(a0, 0.f);
  t1s[y + 8][c] = fmaxf(a1, 0.f);
  __syncthreads();

  float z0 = b2[c], z1 = z0;
  for (int k = 0; k < 64; ++k) {
    float w = W2s[k*64 + c];
    z0 = fmaf(t1s[y][k],     w, z0);
    z1 = fmaf(t1s[y + 8][k], w, z1);
  }
  z0 = fmaxf(z0, 0.f); z1 = fmaxf(z1, 0.f);
  zout[(bid*16 + y)*64 + c]     = z0;
  zout[(bid*16 + y + 8)*64 + c] = z1;

  pp[y][c] = z0 + z1;
  pq[y][c] = z0*z0 + z1*z1;
  __syncthreads();
  if (y == 0) {
    float S = 0.f, Q = 0.f;
#pragma unroll
    for (int r = 0; r < 8; ++r) { S += pp[r][c]; Q += pq[r][c]; }
    P[bid*128 + c]      = S;
    P[bid*128 + 64 + c] = Q;
  }
}

__global__ __launch_bounds__(512) void k_head2(
    const float* __restrict__ z, const float* __restrict__ P,
    const float* __restrict__ gg, const float* __restrict__ be,
    const float* __restrict__ l1w, const float* __restrict__ l1b,
    const float* __restrict__ l2w, const float* __restrict__ l2b,
    const float* __restrict__ nf,
    const float* __restrict__ epw1, const float* __restrict__ epb1,
    _Float16* __restrict__ Ah, _Float16* __restrict__ Bh) {
  __shared__ float W1s[4096];
  __shared__ float W2s[2048];
  __shared__ float Was[2048];
  __shared__ float Wbs[2048];
  __shared__ float sums[4][128];
  __shared__ float scratch[4096];
  __shared__ float scl[64], sft[64];
  int tid = threadIdx.x, c = tid & 63, y = tid >> 6;
  for (int i = tid; i < 4096; i += 512) W1s[i] = l1w[i];
  for (int i = tid; i < 2048; i += 512) { W2s[i] = l2w[i]; Was[i] = epw1[i]; Wbs[i] = epw1[2048 + i]; }

  {
    int c2 = tid & 127, q = tid >> 7;
    float S = 0.f;
    for (int j = q*24; j < q*24 + 24; ++j) S += P[j*128 + c2];
    sums[q][c2] = S;
  }
  __syncthreads();
  if (tid < 64) {
    float S = sums[0][tid] + sums[1][tid] + sums[2][tid] + sums[3][tid];
    float Q = sums[0][64+tid] + sums[1][64+tid] + sums[2][64+tid] + sums[3][64+tid];
    float m  = S * (1.f/NN);
    float iv = rsqrtf(Q * (1.f/NN) - m*m + BN_EPS);
    float sc = iv * gg[tid];
    scl[tid] = sc;
    sft[tid] = be[tid] - m*sc;
  }
  __syncthreads();

  float* t0 = scratch;
  float* t1 = scratch + 1024;
  float* t2 = scratch + 2048;
  int r0 = blockIdx.x*16;

  for (int rr = y; rr < 16; rr += 8)
    t0[rr*64 + c] = lrelu_f(z[(r0 + rr)*64 + c]*scl[c] + sft[c]);
  __syncthreads();
  {
    float a0 = l1b[c], a1 = a0;
    for (int k = 0; k < 64; ++k) {
      float w = W1s[k*64 + c];
      a0 = fmaf(t0[y*64 + k],       w, a0);
      a1 = fmaf(t0[(y + 8)*64 + k], w, a1);
    }
    t1[y*64 + c]       = lrelu_f(a0);
    t1[(y + 8)*64 + c] = lrelu_f(a1);
  }
  __syncthreads();
  if (c < 32) {
    float v0 = l2b[c], v1 = v0;
    for (int k = 0; k < 64; ++k) {
      float w = W2s[k*32 + c];
      v0 = fmaf(t1[y*64 + k],       w, v0);
      v1 = fmaf(t1[(y + 8)*64 + k], w, v1);
    }
    t2[y*32 + c]       = lrelu_f(v0) + nf[(r0 + y)*32 + c];
    t2[(y + 8)*32 + c] = lrelu_f(v1) + nf[(r0 + y + 8)*32 + c];
  }
  __syncthreads();
  {
    float av0 = epb1[c], av1 = av0;
    float bv0 = 0.f, bv1 = 0.f;
    for (int k = 0; k < 32; ++k) {
      float wa = Was[k*64 + c], wb = Wbs[k*64 + c];
      av0 = fmaf(t2[y*32 + k], wa, av0);       bv0 = fmaf(t2[y*32 + k], wb, bv0);
      av1 = fmaf(t2[(y + 8)*32 + k], wa, av1); bv1 = fmaf(t2[(y + 8)*32 + k], wb, bv1);
    }
    Ah[(r0 + y)*64 + c]     = (_Float16)av0;  Bh[(r0 + y)*64 + c]     = (_Float16)bv0;
    Ah[(r0 + y + 8)*64 + c] = (_Float16)av1;  Bh[(r0 + y + 8)*64 + c] = (_Float16)bv1;
  }
}

// ---------------------------------------------------------------------------
// Edge MLP (r16 structure) with HALVED LDS traffic: W2 fragments live in
// VGPRs (+32 regs, ~100 total), only W3 staged in LDS (8KB). Theory: the
// CU-shared LDS pipe was ~2.6x oversubscribed at 16 ds_read_b128/iter across
// ~8 resident waves — the invisible binder that pinned 7 structural variants
// at ~34us. Now 8 ds_read/iter.
__global__ __launch_bounds__(256, 3) void k_edges_f16(
    const _Float16* __restrict__ Ah, const _Float16* __restrict__ Bh,
    const _Float16* __restrict__ Wf,
    const float* __restrict__ b2, const float* __restrict__ b3,
    const float* __restrict__ b4,
    float* __restrict__ out) {
  __shared__ _Float16 Wl[4096];   // W3 only, 8KB
  int tid = threadIdx.x, wid = tid >> 6, lane = tid & 63;
  int c = lane & 15, g = lane >> 4;

  {
    const float4* src = (const float4*)(Wf + 4096);
    float4* dst = (float4*)Wl;
    for (int i = tid; i < 512; i += 256) dst[i] = src[i];
  }

  // W2 fragments resident in VGPRs
  const v8h* wp = (const v8h*)Wf;
  v8h wv2[8];
#pragma unroll
  for (int f = 0; f < 8; ++f) wv2[f] = wp[f*64 + lane];

  f32x4 b2v[4], b3v[4];
  int g4 = g*4;
#pragma unroll
  for (int m = 0; m < 4; ++m)
#pragma unroll
    for (int r = 0; r < 4; ++r) {
      int f = 16*m + g4 + r;
      b2v[m][r] = b2[f]; b3v[m][r] = b3[f];
    }
  float b4v = b4[0];

  v8h w4f0 = wp[1024 + lane];
  v8h w4f1 = wp[1088 + lane];

  V8H zu; zu.f4 = make_float4(0.f, 0.f, 0.f, 0.f);
  const v8h vzero = zu.v;
  const v2hf z2 = { (__fp16)0.f, (__fp16)0.f };
  const f32x4 zz = {0.f, 0.f, 0.f, 0.f};

  const v8h* wl = (const v8h*)Wl;
  __syncthreads();

  int wbase = (blockIdx.x*4 + wid)*2;
  for (int ch = 0; ch < 2; ++ch) {
    int w = wbase + ch;

    int cum, kk, sbase;
    if (w < 1524) { cum = 0; kk = 12; sbase = 0; }
    else {
      cum = 1524; kk = 11; sbase = 127;
      while (kk > 1 && w >= cum + 128*kk) { cum += 128*kk; sbase += 128; --kk; }
    }
    int idx = w - cum;
    int q = idx / kk;
    int s = sbase + q;
    int t0 = s + 1 + ((idx - q*kk) << 7);
    if (t0 >= NN + 64) continue;

    V8H a0, a1;
    a0.f4 = *(const float4*)(Ah + s*64 + g*8);
    a1.f4 = *(const float4*)(Ah + s*64 + 32 + g*8);

    V8H y0a, y1a, y0b, y1b;
    {
      int ta = t0 + c, tb = t0 + 16 + c;
      y0a.f4 = *(const float4*)(Bh + ta*64 + g*8);
      y1a.f4 = *(const float4*)(Bh + ta*64 + 32 + g*8);
      y0b.f4 = *(const float4*)(Bh + tb*64 + g*8);
      y1b.f4 = *(const float4*)(Bh + tb*64 + 32 + g*8);
    }

    for (int it = 0; it < 4; ++it) {
      int tb0 = t0 + (it << 5);
      if (tb0 >= NN) break;
      int ta = tb0 + c, tbx = tb0 + 16 + c;

      // group A: build frags, prefetch, MFMA L2-A (weights from VGPR)
      V8H f0a, f1a;
      f0a.v = __builtin_elementwise_max(a0.v + y0a.v, vzero);
      f1a.v = __builtin_elementwise_max(a1.v + y1a.v, vzero);
      {
        int tna = tb0 + 32 + c;
        y0a.f4 = *(const float4*)(Bh + tna*64 + g*8);
        y1a.f4 = *(const float4*)(Bh + tna*64 + 32 + g*8);
      }
      __builtin_amdgcn_s_setprio(1);
      f32x4 acca[4];
#pragma unroll
      for (int m = 0; m < 4; ++m)
        acca[m] = __builtin_amdgcn_mfma_f32_16x16x32_f16(wv2[m], f0a.v, b2v[m], 0, 0, 0);
#pragma unroll
      for (int m = 0; m < 4; ++m)
        acca[m] = __builtin_amdgcn_mfma_f32_16x16x32_f16(wv2[4 + m], f1a.v, acca[m], 0, 0, 0);
      __builtin_amdgcn_s_setprio(0);

      // group B: build frags, prefetch, MFMA L2-B
      V8H f0b, f1b;
      f0b.v = __builtin_elementwise_max(a0.v + y0b.v, vzero);
      f1b.v = __builtin_elementwise_max(a1.v + y1b.v, vzero);
      {
        int tnb = tb0 + 48 + c;
        y0b.f4 = *(const float4*)(Bh + tnb*64 + g*8);
        y1b.f4 = *(const float4*)(Bh + tnb*64 + 32 + g*8);
      }
      __builtin_amdgcn_s_setprio(1);
      f32x4 accb[4];
#pragma unroll
      for (int m = 0; m < 4; ++m)
        accb[m] = __builtin_amdgcn_mfma_f32_16x16x32_f16(wv2[m], f0b.v, b2v[m], 0, 0, 0);
#pragma unroll
      for (int m = 0; m < 4; ++m)
        accb[m] = __builtin_amdgcn_mfma_f32_16x16x32_f16(wv2[4 + m], f1b.v, accb[m], 0, 0, 0);
      __builtin_amdgcn_s_setprio(0);

      // pack A, L3-A (W3 from LDS); pack B, L3-B
      V8H p0a, p1a, p0b, p1b;
#pragma unroll
      for (int m = 0; m < 2; ++m) {
        p0a.h2[2*m]     = __builtin_elementwise_max(__builtin_amdgcn_cvt_pkrtz(acca[m][0],   acca[m][1]),   z2);
        p0a.h2[2*m + 1] = __builtin_elementwise_max(__builtin_amdgcn_cvt_pkrtz(acca[m][2],   acca[m][3]),   z2);
        p1a.h2[2*m]     = __builtin_elementwise_max(__builtin_amdgcn_cvt_pkrtz(acca[m+2][0], acca[m+2][1]), z2);
        p1a.h2[2*m + 1] = __builtin_elementwise_max(__builtin_amdgcn_cvt_pkrtz(acca[m+2][2], acca[m+2][3]), z2);
      }
      __builtin_amdgcn_s_setprio(1);
      f32x4 ac3a[4];
#pragma unroll
      for (int m = 0; m < 4; ++m)
        ac3a[m] = __builtin_amdgcn_mfma_f32_16x16x32_f16(wl[m*64 + lane], p0a.v, b3v[m], 0, 0, 0);
#pragma unroll
      for (int m = 0; m < 4; ++m)
        ac3a[m] = __builtin_amdgcn_mfma_f32_16x16x32_f16(wl[(4 + m)*64 + lane], p1a.v, ac3a[m], 0, 0, 0);
      __builtin_amdgcn_s_setprio(0);

#pragma unroll
      for (int m = 0; m < 2; ++m) {
        p0b.h2[2*m]     = __builtin_elementwise_max(__builtin_amdgcn_cvt_pkrtz(accb[m][0],   accb[m][1]),   z2);
        p0b.h2[2*m + 1] = __builtin_elementwise_max(__builtin_amdgcn_cvt_pkrtz(accb[m][2],   accb[m][3]),   z2);
        p1b.h2[2*m]     = __builtin_elementwise_max(__builtin_amdgcn_cvt_pkrtz(accb[m+2][0], accb[m+2][1]), z2);
        p1b.h2[2*m + 1] = __builtin_elementwise_max(__builtin_amdgcn_cvt_pkrtz(accb[m+2][2], accb[m+2][3]), z2);
      }
      __builtin_amdgcn_s_setprio(1);
      f32x4 ac3b[4];
#pragma unroll
      for (int m = 0; m < 4; ++m)
        ac3b[m] = __builtin_amdgcn_mfma_f32_16x16x32_f16(wl[m*64 + lane], p0b.v, b3v[m], 0, 0, 0);
#pragma unroll
      for (int m = 0; m < 4; ++m)
        ac3b[m] = __builtin_amdgcn_mfma_f32_16x16x32_f16(wl[(4 + m)*64 + lane], p1b.v, ac3b[m], 0, 0, 0);
      __builtin_amdgcn_s_setprio(0);

      // layer 4 via MFMA (w4 row-0 A-frag; logit in lanes 0-15 reg0)
      V8H q0a, q1a, q0b, q1b;
#pragma unroll
      for (int m = 0; m < 2; ++m) {
        q0a.h2[2*m]     = __builtin_elementwise_max(__builtin_amdgcn_cvt_pkrtz(ac3a[m][0],   ac3a[m][1]),   z2);
        q0a.h2[2*m + 1] = __builtin_elementwise_max(__builtin_amdgcn_cvt_pkrtz(ac3a[m][2],   ac3a[m][3]),   z2);
        q1a.h2[2*m]     = __builtin_elementwise_max(__builtin_amdgcn_cvt_pkrtz(ac3a[m+2][0], ac3a[m+2][1]), z2);
        q1a.h2[2*m + 1] = __builtin_elementwise_max(__builtin_amdgcn_cvt_pkrtz(ac3a[m+2][2], ac3a[m+2][3]), z2);
        q0b.h2[2*m]     = __builtin_elementwise_max(__builtin_amdgcn_cvt_pkrtz(ac3b[m][0],   ac3b[m][1]),   z2);
        q0b.h2[2*m + 1] = __builtin_elementwise_max(__builtin_amdgcn_cvt_pkrtz(ac3b[m][2],   ac3b[m][3]),   z2);
        q1b.h2[2*m]     = __builtin_elementwise_max(__builtin_amdgcn_cvt_pkrtz(ac3b[m+2][0], ac3b[m+2][1]), z2);
        q1b.h2[2*m + 1] = __builtin_elementwise_max(__builtin_amdgcn_cvt_pkrtz(ac3b[m+2][2], ac3b[m+2][3]), z2);
      }
      __builtin_amdgcn_s_setprio(1);
      f32x4 da = __builtin_amdgcn_mfma_f32_16x16x32_f16(w4f0, q0a.v, zz, 0, 0, 0);
      f32x4 db = __builtin_amdgcn_mfma_f32_16x16x32_f16(w4f0, q0b.v, zz, 0, 0, 0);
      da = __builtin_amdgcn_mfma_f32_16x16x32_f16(w4f1, q1a.v, da, 0, 0, 0);
      db = __builtin_amdgcn_mfma_f32_16x16x32_f16(w4f1, q1b.v, db, 0, 0, 0);
      __builtin_amdgcn_s_setprio(0);

      float eza = __builtin_amdgcn_exp2f(-1.44269504f * (da[0] + b4v));
      float ezb = __builtin_amdgcn_exp2f(-1.44269504f * (db[0] + b4v));
      float proba = __builtin_amdgcn_rcpf(1.f + eza);
      float probb = __builtin_amdgcn_rcpf(1.f + ezb);
      if (lane < 16) {
        if (ta < NN)  __builtin_nontemporal_store(proba, &out[s*NN + ta]);
        if (tbx < NN) __builtin_nontemporal_store(probb, &out[s*NN + tbx]);
      }
    }
  }
}

// mirror: lower = upper^T, diag = 0. NT loads/stores.
__global__ __launch_bounds__(256) void k_mirror(float* __restrict__ out) {
  __shared__ float tile[32][33];
  int k = blockIdx.x;
  int bi = (int)((sqrtf(8.f*k + 1.f) - 1.f)*0.5f);
  while (bi*(bi + 1)/2 > k) --bi;
  while ((bi + 1)*(bi + 2)/2 <= k) ++bi;
  int bj = k - bi*(bi + 1)/2;
  int i0 = bi*32, j0 = bj*32;
  int tx = threadIdx.x & 31, ty = threadIdx.x >> 5;
#pragma unroll
  for (int r = 0; r < 4; ++r)
    tile[ty + r*8][tx] = __builtin_nontemporal_load(&out[(j0 + ty + r*8)*NN + i0 + tx]);
  __syncthreads();
#pragma unroll
  for (int r = 0; r < 4; ++r) {
    int row = ty + r*8;
    int i = i0 + row, j = j0 + tx;
    if (bi > bj)      __builtin_nontemporal_store(tile[tx][row], &out[i*NN + j]);
    else if (i > j)   __builtin_nontemporal_store(tile[tx][row], &out[i*NN + j]);
    else if (i == j)  __builtin_nontemporal_store(0.f, &out[i*NN + j]);
  }
}

// ---------------------------------------------------------------------------
extern "C" void kernel_launch(void* const* d_in, const int* in_sizes, int n_in,
                              void* d_out, int out_size, void* d_ws, size_t ws_size,
                              hipStream_t stream) {
  const float* nf     = (const float*)d_in[1];
  const float* c1_eps = (const float*)d_in[2];
  const float* c1_w1  = (const float*)d_in[3];
  const float* c1_b1  = (const float*)d_in[4];
  const float* c1_w2  = (const float*)d_in[5];
  const float* c1_b2  = (const float*)d_in[6];
  const float* c1_g   = (const float*)d_in[7];
  const float* c1_be  = (const float*)d_in[8];
  const float* cv_eps = (const float*)d_in[9];
  const float* cv_w1  = (const float*)d_in[10];
  const float* cv_b1  = (const float*)d_in[11];
  const float* cv_w2  = (const float*)d_in[12];
  const float* cv_b2  = (const float*)d_in[13];
  const float* cv_g   = (const float*)d_in[14];
  const float* cv_be  = (const float*)d_in[15];
  const float* lin1_w = (const float*)d_in[16];
  const float* lin1_b = (const float*)d_in[17];
  const float* lin2_w = (const float*)d_in[18];
  const float* lin2_b = (const float*)d_in[19];
  const float* ep_w1  = (const float*)d_in[20];
  const float* ep_b1  = (const float*)d_in[21];
  const float* ep_w2  = (const float*)d_in[22];
  const float* ep_b2  = (const float*)d_in[23];
  const float* ep_w3  = (const float*)d_in[24];
  const float* ep_b3  = (const float*)d_in[25];
  const float* ep_w4  = (const float*)d_in[26];
  const float* ep_b4  = (const float*)d_in[27];

  float* ws = (float*)d_ws;
  float* zA    = ws;                       // [NN*64]
  float* zB    = zA + NN*64;               // [NN*64]
  float* hbuf  = zB + NN*64;               // [NN*64]
  float* H     = hbuf + NN*64;             // [96*64]
  float* P     = H + 96*64;                // [96*128]
  _Float16* Ah = (_Float16*)(P + 96*128);  // [NN*64] f16
  _Float16* Bh = Ah + NN*64;               // [NN*64] f16
  _Float16* Wf = Bh + NN*64;               // [9216] f16 (absorbs Bh overread)

  float* out = (float*)d_out;

  k_first<<<132, 256, 0, stream>>>(nf, H, ep_w2, ep_w3, ep_w4, Wf);
  k_mmp<32><<<96, 512, 0, stream>>>(nf, H, c1_eps, c1_w1, c1_b1, c1_w2, c1_b2, zA, P);

  k_bn<<<96, 256, 0, stream>>>(zA, P, c1_g, c1_be, hbuf, H);
  k_mmp<64><<<96, 512, 0, stream>>>(hbuf, H, cv_eps, cv_w1, cv_b1, cv_w2, cv_b2, zB, P);

  k_bn<<<96, 256, 0, stream>>>(zB, P, cv_g, cv_be, hbuf, H);
  k_mmp<64><<<96, 512, 0, stream>>>(hbuf, H, cv_eps + 1,
      cv_w1 + HH*HH, cv_b1 + HH, cv_w2 + HH*HH, cv_b2 + HH, zA, P);

  k_head2<<<96, 512, 0, stream>>>(zA, P, cv_g + HH, cv_be + HH,
                                  lin1_w, lin1_b, lin2_w, lin2_b, nf,
                                  ep_w1, ep_b1, Ah, Bh);

  k_edges_f16<<<EBLK, 256, 0, stream>>>(Ah, Bh, Wf, ep_b2, ep_b3, ep_b4, out);
  k_mirror<<<1176, 256, 0, stream>>>(out);
}

// Round 18
// 79.320 us; speedup vs baseline: 1.1606x; 1.1606x over previous
//
#include <hip/hip_runtime.h>
#include <math.h>

#define NN 1536
#define FF 32
#define HH 64
#define EE (NN*(NN-1)/2)
#define EBLK 1248          // 1248 blocks * 4 waves * 2 chunks = 9984 >= 9972
#define BN_EPS 1e-5f
#define SLOPE 0.01f

typedef _Float16 v8h   __attribute__((ext_vector_type(8)));
typedef __fp16   v2hf  __attribute__((ext_vector_type(2)));
typedef float    f32x4 __attribute__((ext_vector_type(4)));

union V8H { v8h v; v2hf h2[4]; float4 f4; };

__device__ __forceinline__ float lrelu_f(float v){ return v >= 0.f ? v : SLOPE*v; }

// ---------------------------------------------------------------------------
// Node pipeline (r12 structure: partials flow through kernel boundaries).
__global__ __launch_bounds__(256) void k_first(
    const float* __restrict__ nf, float* __restrict__ H,
    const float* __restrict__ pw2, const float* __restrict__ pw3,
    const float* __restrict__ pw4,
    _Float16* __restrict__ pwf) {
  int bid = blockIdx.x, tid = threadIdx.x;
  if (bid >= 96) {
    int i = (bid - 96)*256 + tid;     // 9216 elems over 36 blocks
    if (i < 8192) {
      int mat = i >> 12, r = i & 4095;
      int k = r >> 6, cout = r & 63;
      int m = cout >> 4, cc = cout & 15;
      int q, g, b;
      if (mat == 0) { q = k >> 5; g = (k >> 3) & 3; b = k & 7; }
      else { int mF = k >> 4; g = (k >> 2) & 3; int rr = k & 3; q = mF >> 1; b = ((mF & 1) << 2) | rr; }
      const float* W = mat ? pw3 : pw2;
      pwf[mat*4096 + ((q*4 + m)*64 + (g*16 + cc))*8 + b] = (_Float16)W[r];
    } else if (i < 9216) {
      int e = i - 8192;
      int fi = e >> 9, rem = e & 511;
      int lane = rem >> 3, b = rem & 7;
      int g = lane >> 4, r = lane & 15;
      int q = b >> 2, j = b & 3;
      float val = (r == 0) ? pw4[fi*32 + 16*q + 4*g + j] : 0.f;
      pwf[i] = (_Float16)val;
    }
    return;
  }
  __shared__ float part[8][32];
  int c = tid & 31, y = tid >> 5;
  float s = nf[(bid*16 + y)*32 + c] + nf[(bid*16 + y + 8)*32 + c];
  part[y][c] = s;
  __syncthreads();
  if (y == 0) {
    float S = 0.f;
#pragma unroll
    for (int r = 0; r < 8; ++r) S += part[r][c];
    H[bid*64 + c] = S;
  }
}

__global__ __launch_bounds__(256) void k_bn(
    const float* __restrict__ z, const float* __restrict__ P,
    const float* __restrict__ gg, const float* __restrict__ be,
    float* __restrict__ hbuf, float* __restrict__ H) {
  __shared__ float sums[2][128];
  __shared__ float scl[64], sft[64];
  __shared__ float part[4][64];
  int tid = threadIdx.x, bid = blockIdx.x;
  {
    int c2 = tid & 127, half = tid >> 7;
    float S0 = 0.f, S1 = 0.f;
    int j0 = half*48;
    for (int j = j0; j < j0 + 48; j += 2) { S0 += P[j*128 + c2]; S1 += P[(j+1)*128 + c2]; }
    sums[half][c2] = S0 + S1;
  }
  __syncthreads();
  if (tid < 64) {
    float S = sums[0][tid] + sums[1][tid];
    float Q = sums[0][64 + tid] + sums[1][64 + tid];
    float m  = S * (1.f/NN);
    float iv = rsqrtf(Q * (1.f/NN) - m*m + BN_EPS);
    float sc = iv * gg[tid];
    scl[tid] = sc;
    sft[tid] = be[tid] - m*sc;
  }
  __syncthreads();
  int c = tid & 63, y = tid >> 6;
  float sc = scl[c], sh = sft[c];
  float hs = 0.f;
#pragma unroll
  for (int i = 0; i < 4; ++i) {
    int rr = y + 4*i;
    float h = lrelu_f(z[(bid*16 + rr)*64 + c]*sc + sh);
    hbuf[(bid*16 + rr)*64 + c] = h;
    hs += h;
  }
  part[y][c] = hs;
  __syncthreads();
  if (y == 0)
    H[bid*64 + c] = part[0][c] + part[1][c] + part[2][c] + part[3][c];
}

template<int DIN>
__global__ __launch_bounds__(512) void k_mmp(
    const float* __restrict__ hb, const float* __restrict__ H,
    const float* __restrict__ eps_p,
    const float* __restrict__ W1, const float* __restrict__ b1,
    const float* __restrict__ W2, const float* __restrict__ b2,
    float* __restrict__ zout, float* __restrict__ P) {
  __shared__ float W1s[DIN*64];
  __shared__ float W2s[4096];
  __shared__ float red[8][64];
  __shared__ float pf[64];
  __shared__ float hh[16][DIN];
  __shared__ float uls[16*DIN];
  __shared__ float t1s[16][64];
  __shared__ float pp[8][64], pq[8][64];
  int tid = threadIdx.x, bid = blockIdx.x;
  int c = tid & 63, y = tid >> 6;
  for (int i = tid; i < DIN*64; i += 512) W1s[i] = W1[i];
  for (int i = tid; i < 4096; i += 512)   W2s[i] = W2[i];

  {
    float s = 0.f;
    if (c < DIN) for (int j = y; j < bid; j += 8) s += H[j*64 + c];
    red[y][c] = s;
  }
  if (c < DIN) {
    hh[y][c]     = hb[(bid*16 + y)*DIN + c];
    hh[y + 8][c] = hb[(bid*16 + y + 8)*DIN + c];
  }
  __syncthreads();
  if (y == 0 && c < DIN) {
    float S = 0.f;
#pragma unroll
    for (int r = 0; r < 8; ++r) S += red[r][c];
    pf[c] = S;
  }
  __syncthreads();

  float e1 = 1.f + eps_p[0];
  if (c < DIN) {
    for (int rr = y; rr < 16; rr += 8) {
      float run = pf[c];
      for (int r2 = 0; r2 < rr; ++r2) run += hh[r2][c];
      uls[rr*DIN + c] = e1*hh[rr][c] + run;
    }
  }
  __syncthreads();

  float a0 = b1[c], a1 = a0;
  for (int k = 0; k < DIN; ++k) {
    float w = W1s[k*64 + c];
    a0 = fmaf(uls[y*DIN + k],       w, a0);
    a1 = fmaf(uls[(y + 8)*DIN + k], w, a1);
  }
  t1s[y][c]     = fmaxf(a0, 0.f);
  t1s[y + 8][c] = fmaxf(a1, 0.f);
  __syncthreads();

  float z0 = b2[c], z1 = z0;
  for (int k = 0; k < 64; ++k) {
    float w = W2s[k*64 + c];
    z0 = fmaf(t1s[y][k],     w, z0);
    z1 = fmaf(t1s[y + 8][k], w, z1);
  }
  z0 = fmaxf(z0, 0.f); z1 = fmaxf(z1, 0.f);
  zout[(bid*16 + y)*64 + c]     = z0;
  zout[(bid*16 + y + 8)*64 + c] = z1;

  pp[y][c] = z0 + z1;
  pq[y][c] = z0*z0 + z1*z1;
  __syncthreads();
  if (y == 0) {
    float S = 0.f, Q = 0.f;
#pragma unroll
    for (int r = 0; r < 8; ++r) { S += pp[r][c]; Q += pq[r][c]; }
    P[bid*128 + c]      = S;
    P[bid*128 + 64 + c] = Q;
  }
}

__global__ __launch_bounds__(512) void k_head2(
    const float* __restrict__ z, const float* __restrict__ P,
    const float* __restrict__ gg, const float* __restrict__ be,
    const float* __restrict__ l1w, const float* __restrict__ l1b,
    const float* __restrict__ l2w, const float* __restrict__ l2b,
    const float* __restrict__ nf,
    const float* __restrict__ epw1, const float* __restrict__ epb1,
    _Float16* __restrict__ Ah, _Float16* __restrict__ Bh) {
  __shared__ float W1s[4096];
  __shared__ float W2s[2048];
  __shared__ float Was[2048];
  __shared__ float Wbs[2048];
  __shared__ float sums[4][128];
  __shared__ float scratch[4096];
  __shared__ float scl[64], sft[64];
  int tid = threadIdx.x, c = tid & 63, y = tid >> 6;
  for (int i = tid; i < 4096; i += 512) W1s[i] = l1w[i];
  for (int i = tid; i < 2048; i += 512) { W2s[i] = l2w[i]; Was[i] = epw1[i]; Wbs[i] = epw1[2048 + i]; }

  {
    int c2 = tid & 127, q = tid >> 7;
    float S = 0.f;
    for (int j = q*24; j < q*24 + 24; ++j) S += P[j*128 + c2];
    sums[q][c2] = S;
  }
  __syncthreads();
  if (tid < 64) {
    float S = sums[0][tid] + sums[1][tid] + sums[2][tid] + sums[3][tid];
    float Q = sums[0][64+tid] + sums[1][64+tid] + sums[2][64+tid] + sums[3][64+tid];
    float m  = S * (1.f/NN);
    float iv = rsqrtf(Q * (1.f/NN) - m*m + BN_EPS);
    float sc = iv * gg[tid];
    scl[tid] = sc;
    sft[tid] = be[tid] - m*sc;
  }
  __syncthreads();

  float* t0 = scratch;
  float* t1 = scratch + 1024;
  float* t2 = scratch + 2048;
  int r0 = blockIdx.x*16;

  for (int rr = y; rr < 16; rr += 8)
    t0[rr*64 + c] = lrelu_f(z[(r0 + rr)*64 + c]*scl[c] + sft[c]);
  __syncthreads();
  {
    float a0 = l1b[c], a1 = a0;
    for (int k = 0; k < 64; ++k) {
      float w = W1s[k*64 + c];
      a0 = fmaf(t0[y*64 + k],       w, a0);
      a1 = fmaf(t0[(y + 8)*64 + k], w, a1);
    }
    t1[y*64 + c]       = lrelu_f(a0);
    t1[(y + 8)*64 + c] = lrelu_f(a1);
  }
  __syncthreads();
  if (c < 32) {
    float v0 = l2b[c], v1 = v0;
    for (int k = 0; k < 64; ++k) {
      float w = W2s[k*32 + c];
      v0 = fmaf(t1[y*64 + k],       w, v0);
      v1 = fmaf(t1[(y + 8)*64 + k], w, v1);
    }
    t2[y*32 + c]       = lrelu_f(v0) + nf[(r0 + y)*32 + c];
    t2[(y + 8)*32 + c] = lrelu_f(v1) + nf[(r0 + y + 8)*32 + c];
  }
  __syncthreads();
  {
    float av0 = epb1[c], av1 = av0;
    float bv0 = 0.f, bv1 = 0.f;
    for (int k = 0; k < 32; ++k) {
      float wa = Was[k*64 + c], wb = Wbs[k*64 + c];
      av0 = fmaf(t2[y*32 + k], wa, av0);       bv0 = fmaf(t2[y*32 + k], wb, bv0);
      av1 = fmaf(t2[(y + 8)*32 + k], wa, av1); bv1 = fmaf(t2[(y + 8)*32 + k], wb, bv1);
    }
    Ah[(r0 + y)*64 + c]     = (_Float16)av0;  Bh[(r0 + y)*64 + c]     = (_Float16)bv0;
    Ah[(r0 + y + 8)*64 + c] = (_Float16)av1;  Bh[(r0 + y + 8)*64 + c] = (_Float16)bv1;
  }
}

// ---------------------------------------------------------------------------
// Edge MLP — round-16 best configuration (REVERT of r17's regression):
// both weight matrices LDS-staged (r17 showed VGPR-weights get rematerialized
// from global at 84-reg allocation: FETCH 1.1->6.0 MB), persistent dual-group,
// MFMA layer-4, NT stores, staggered per-group builds.
__global__ __launch_bounds__(256, 3) void k_edges_f16(
    const _Float16* __restrict__ Ah, const _Float16* __restrict__ Bh,
    const _Float16* __restrict__ Wf,
    const float* __restrict__ b2, const float* __restrict__ b3,
    const float* __restrict__ b4,
    float* __restrict__ out) {
  __shared__ _Float16 Wl[8192];
  int tid = threadIdx.x, wid = tid >> 6, lane = tid & 63;
  int c = lane & 15, g = lane >> 4;

  {
    const float4* src = (const float4*)Wf;
    float4* dst = (float4*)Wl;
    for (int i = tid; i < 1024; i += 256) dst[i] = src[i];
  }

  f32x4 b2v[4], b3v[4];
  int g4 = g*4;
#pragma unroll
  for (int m = 0; m < 4; ++m)
#pragma unroll
    for (int r = 0; r < 4; ++r) {
      int f = 16*m + g4 + r;
      b2v[m][r] = b2[f]; b3v[m][r] = b3[f];
    }
  float b4v = b4[0];

  const v8h* wp = (const v8h*)Wf;
  v8h w4f0 = wp[1024 + lane];
  v8h w4f1 = wp[1088 + lane];

  V8H zu; zu.f4 = make_float4(0.f, 0.f, 0.f, 0.f);
  const v8h vzero = zu.v;
  const v2hf z2 = { (__fp16)0.f, (__fp16)0.f };
  const f32x4 zz = {0.f, 0.f, 0.f, 0.f};

  const v8h* wl = (const v8h*)Wl;
  __syncthreads();

  int wbase = (blockIdx.x*4 + wid)*2;
  for (int ch = 0; ch < 2; ++ch) {
    int w = wbase + ch;

    int cum, kk, sbase;
    if (w < 1524) { cum = 0; kk = 12; sbase = 0; }
    else {
      cum = 1524; kk = 11; sbase = 127;
      while (kk > 1 && w >= cum + 128*kk) { cum += 128*kk; sbase += 128; --kk; }
    }
    int idx = w - cum;
    int q = idx / kk;
    int s = sbase + q;
    int t0 = s + 1 + ((idx - q*kk) << 7);
    if (t0 >= NN + 64) continue;

    V8H a0, a1;
    a0.f4 = *(const float4*)(Ah + s*64 + g*8);
    a1.f4 = *(const float4*)(Ah + s*64 + 32 + g*8);

    V8H y0a, y1a, y0b, y1b;
    {
      int ta = t0 + c, tb = t0 + 16 + c;
      y0a.f4 = *(const float4*)(Bh + ta*64 + g*8);
      y1a.f4 = *(const float4*)(Bh + ta*64 + 32 + g*8);
      y0b.f4 = *(const float4*)(Bh + tb*64 + g*8);
      y1b.f4 = *(const float4*)(Bh + tb*64 + 32 + g*8);
    }

    for (int it = 0; it < 4; ++it) {
      int tb0 = t0 + (it << 5);
      if (tb0 >= NN) break;
      int ta = tb0 + c, tbx = tb0 + 16 + c;

      // group A: build frags, prefetch, MFMA L2-A
      V8H f0a, f1a;
      f0a.v = __builtin_elementwise_max(a0.v + y0a.v, vzero);
      f1a.v = __builtin_elementwise_max(a1.v + y1a.v, vzero);
      {
        int tna = tb0 + 32 + c;
        y0a.f4 = *(const float4*)(Bh + tna*64 + g*8);
        y1a.f4 = *(const float4*)(Bh + tna*64 + 32 + g*8);
      }
      __builtin_amdgcn_s_setprio(1);
      f32x4 acca[4];
#pragma unroll
      for (int m = 0; m < 4; ++m)
        acca[m] = __builtin_amdgcn_mfma_f32_16x16x32_f16(wl[m*64 + lane], f0a.v, b2v[m], 0, 0, 0);
#pragma unroll
      for (int m = 0; m < 4; ++m)
        acca[m] = __builtin_amdgcn_mfma_f32_16x16x32_f16(wl[(4 + m)*64 + lane], f1a.v, acca[m], 0, 0, 0);
      __builtin_amdgcn_s_setprio(0);

      // group B: build frags, prefetch, MFMA L2-B
      V8H f0b, f1b;
      f0b.v = __builtin_elementwise_max(a0.v + y0b.v, vzero);
      f1b.v = __builtin_elementwise_max(a1.v + y1b.v, vzero);
      {
        int tnb = tb0 + 48 + c;
        y0b.f4 = *(const float4*)(Bh + tnb*64 + g*8);
        y1b.f4 = *(const float4*)(Bh + tnb*64 + 32 + g*8);
      }
      __builtin_amdgcn_s_setprio(1);
      f32x4 accb[4];
#pragma unroll
      for (int m = 0; m < 4; ++m)
        accb[m] = __builtin_amdgcn_mfma_f32_16x16x32_f16(wl[m*64 + lane], f0b.v, b2v[m], 0, 0, 0);
#pragma unroll
      for (int m = 0; m < 4; ++m)
        accb[m] = __builtin_amdgcn_mfma_f32_16x16x32_f16(wl[(4 + m)*64 + lane], f1b.v, accb[m], 0, 0, 0);
      __builtin_amdgcn_s_setprio(0);

      // pack A, L3-A; pack B, L3-B
      V8H p0a, p1a, p0b, p1b;
#pragma unroll
      for (int m = 0; m < 2; ++m) {
        p0a.h2[2*m]     = __builtin_elementwise_max(__builtin_amdgcn_cvt_pkrtz(acca[m][0],   acca[m][1]),   z2);
        p0a.h2[2*m + 1] = __builtin_elementwise_max(__builtin_amdgcn_cvt_pkrtz(acca[m][2],   acca[m][3]),   z2);
        p1a.h2[2*m]     = __builtin_elementwise_max(__builtin_amdgcn_cvt_pkrtz(acca[m+2][0], acca[m+2][1]), z2);
        p1a.h2[2*m + 1] = __builtin_elementwise_max(__builtin_amdgcn_cvt_pkrtz(acca[m+2][2], acca[m+2][3]), z2);
      }
      __builtin_amdgcn_s_setprio(1);
      f32x4 ac3a[4];
#pragma unroll
      for (int m = 0; m < 4; ++m)
        ac3a[m] = __builtin_amdgcn_mfma_f32_16x16x32_f16(wl[512 + m*64 + lane], p0a.v, b3v[m], 0, 0, 0);
#pragma unroll
      for (int m = 0; m < 4; ++m)
        ac3a[m] = __builtin_amdgcn_mfma_f32_16x16x32_f16(wl[512 + (4 + m)*64 + lane], p1a.v, ac3a[m], 0, 0, 0);
      __builtin_amdgcn_s_setprio(0);

#pragma unroll
      for (int m = 0; m < 2; ++m) {
        p0b.h2[2*m]     = __builtin_elementwise_max(__builtin_amdgcn_cvt_pkrtz(accb[m][0],   accb[m][1]),   z2);
        p0b.h2[2*m + 1] = __builtin_elementwise_max(__builtin_amdgcn_cvt_pkrtz(accb[m][2],   accb[m][3]),   z2);
        p1b.h2[2*m]     = __builtin_elementwise_max(__builtin_amdgcn_cvt_pkrtz(accb[m+2][0], accb[m+2][1]), z2);
        p1b.h2[2*m + 1] = __builtin_elementwise_max(__builtin_amdgcn_cvt_pkrtz(accb[m+2][2], accb[m+2][3]), z2);
      }
      __builtin_amdgcn_s_setprio(1);
      f32x4 ac3b[4];
#pragma unroll
      for (int m = 0; m < 4; ++m)
        ac3b[m] = __builtin_amdgcn_mfma_f32_16x16x32_f16(wl[512 + m*64 + lane], p0b.v, b3v[m], 0, 0, 0);
#pragma unroll
      for (int m = 0; m < 4; ++m)
        ac3b[m] = __builtin_amdgcn_mfma_f32_16x16x32_f16(wl[512 + (4 + m)*64 + lane], p1b.v, ac3b[m], 0, 0, 0);
      __builtin_amdgcn_s_setprio(0);

      // layer 4 via MFMA (w4 row-0 A-frag; logit in lanes 0-15 reg0)
      V8H q0a, q1a, q0b, q1b;
#pragma unroll
      for (int m = 0; m < 2; ++m) {
        q0a.h2[2*m]     = __builtin_elementwise_max(__builtin_amdgcn_cvt_pkrtz(ac3a[m][0],   ac3a[m][1]),   z2);
        q0a.h2[2*m + 1] = __builtin_elementwise_max(__builtin_amdgcn_cvt_pkrtz(ac3a[m][2],   ac3a[m][3]),   z2);
        q1a.h2[2*m]     = __builtin_elementwise_max(__builtin_amdgcn_cvt_pkrtz(ac3a[m+2][0], ac3a[m+2][1]), z2);
        q1a.h2[2*m + 1] = __builtin_elementwise_max(__builtin_amdgcn_cvt_pkrtz(ac3a[m+2][2], ac3a[m+2][3]), z2);
        q0b.h2[2*m]     = __builtin_elementwise_max(__builtin_amdgcn_cvt_pkrtz(ac3b[m][0],   ac3b[m][1]),   z2);
        q0b.h2[2*m + 1] = __builtin_elementwise_max(__builtin_amdgcn_cvt_pkrtz(ac3b[m][2],   ac3b[m][3]),   z2);
        q1b.h2[2*m]     = __builtin_elementwise_max(__builtin_amdgcn_cvt_pkrtz(ac3b[m+2][0], ac3b[m+2][1]), z2);
        q1b.h2[2*m + 1] = __builtin_elementwise_max(__builtin_amdgcn_cvt_pkrtz(ac3b[m+2][2], ac3b[m+2][3]), z2);
      }
      __builtin_amdgcn_s_setprio(1);
      f32x4 da = __builtin_amdgcn_mfma_f32_16x16x32_f16(w4f0, q0a.v, zz, 0, 0, 0);
      f32x4 db = __builtin_amdgcn_mfma_f32_16x16x32_f16(w4f0, q0b.v, zz, 0, 0, 0);
      da = __builtin_amdgcn_mfma_f32_16x16x32_f16(w4f1, q1a.v, da, 0, 0, 0);
      db = __builtin_amdgcn_mfma_f32_16x16x32_f16(w4f1, q1b.v, db, 0, 0, 0);
      __builtin_amdgcn_s_setprio(0);

      float eza = __builtin_amdgcn_exp2f(-1.44269504f * (da[0] + b4v));
      float ezb = __builtin_amdgcn_exp2f(-1.44269504f * (db[0] + b4v));
      float proba = __builtin_amdgcn_rcpf(1.f + eza);
      float probb = __builtin_amdgcn_rcpf(1.f + ezb);
      if (lane < 16) {
        if (ta < NN)  __builtin_nontemporal_store(proba, &out[s*NN + ta]);
        if (tbx < NN) __builtin_nontemporal_store(probb, &out[s*NN + tbx]);
      }
    }
  }
}

// mirror: lower = upper^T, diag = 0. NT loads/stores.
__global__ __launch_bounds__(256) void k_mirror(float* __restrict__ out) {
  __shared__ float tile[32][33];
  int k = blockIdx.x;
  int bi = (int)((sqrtf(8.f*k + 1.f) - 1.f)*0.5f);
  while (bi*(bi + 1)/2 > k) --bi;
  while ((bi + 1)*(bi + 2)/2 <= k) ++bi;
  int bj = k - bi*(bi + 1)/2;
  int i0 = bi*32, j0 = bj*32;
  int tx = threadIdx.x & 31, ty = threadIdx.x >> 5;
#pragma unroll
  for (int r = 0; r < 4; ++r)
    tile[ty + r*8][tx] = __builtin_nontemporal_load(&out[(j0 + ty + r*8)*NN + i0 + tx]);
  __syncthreads();
#pragma unroll
  for (int r = 0; r < 4; ++r) {
    int row = ty + r*8;
    int i = i0 + row, j = j0 + tx;
    if (bi > bj)      __builtin_nontemporal_store(tile[tx][row], &out[i*NN + j]);
    else if (i > j)   __builtin_nontemporal_store(tile[tx][row], &out[i*NN + j]);
    else if (i == j)  __builtin_nontemporal_store(0.f, &out[i*NN + j]);
  }
}

// ---------------------------------------------------------------------------
extern "C" void kernel_launch(void* const* d_in, const int* in_sizes, int n_in,
                              void* d_out, int out_size, void* d_ws, size_t ws_size,
                              hipStream_t stream) {
  const float* nf     = (const float*)d_in[1];
  const float* c1_eps = (const float*)d_in[2];
  const float* c1_w1  = (const float*)d_in[3];
  const float* c1_b1  = (const float*)d_in[4];
  const float* c1_w2  = (const float*)d_in[5];
  const float* c1_b2  = (const float*)d_in[6];
  const float* c1_g   = (const float*)d_in[7];
  const float* c1_be  = (const float*)d_in[8];
  const float* cv_eps = (const float*)d_in[9];
  const float* cv_w1  = (const float*)d_in[10];
  const float* cv_b1  = (const float*)d_in[11];
  const float* cv_w2  = (const float*)d_in[12];
  const float* cv_b2  = (const float*)d_in[13];
  const float* cv_g   = (const float*)d_in[14];
  const float* cv_be  = (const float*)d_in[15];
  const float* lin1_w = (const float*)d_in[16];
  const float* lin1_b = (const float*)d_in[17];
  const float* lin2_w = (const float*)d_in[18];
  const float* lin2_b = (const float*)d_in[19];
  const float* ep_w1  = (const float*)d_in[20];
  const float* ep_b1  = (const float*)d_in[21];
  const float* ep_w2  = (const float*)d_in[22];
  const float* ep_b2  = (const float*)d_in[23];
  const float* ep_w3  = (const float*)d_in[24];
  const float* ep_b3  = (const float*)d_in[25];
  const float* ep_w4  = (const float*)d_in[26];
  const float* ep_b4  = (const float*)d_in[27];

  float* ws = (float*)d_ws;
  float* zA    = ws;                       // [NN*64]
  float* zB    = zA + NN*64;               // [NN*64]
  float* hbuf  = zB + NN*64;               // [NN*64]
  float* H     = hbuf + NN*64;             // [96*64]
  float* P     = H + 96*64;                // [96*128]
  _Float16* Ah = (_Float16*)(P + 96*128);  // [NN*64] f16
  _Float16* Bh = Ah + NN*64;               // [NN*64] f16
  _Float16* Wf = Bh + NN*64;               // [9216] f16 (absorbs Bh overread)

  float* out = (float*)d_out;

  k_first<<<132, 256, 0, stream>>>(nf, H, ep_w2, ep_w3, ep_w4, Wf);
  k_mmp<32><<<96, 512, 0, stream>>>(nf, H, c1_eps, c1_w1, c1_b1, c1_w2, c1_b2, zA, P);

  k_bn<<<96, 256, 0, stream>>>(zA, P, c1_g, c1_be, hbuf, H);
  k_mmp<64><<<96, 512, 0, stream>>>(hbuf, H, cv_eps, cv_w1, cv_b1, cv_w2, cv_b2, zB, P);

  k_bn<<<96, 256, 0, stream>>>(zB, P, cv_g, cv_be, hbuf, H);
  k_mmp<64><<<96, 512, 0, stream>>>(hbuf, H, cv_eps + 1,
      cv_w1 + HH*HH, cv_b1 + HH, cv_w2 + HH*HH, cv_b2 + HH, zA, P);

  k_head2<<<96, 512, 0, stream>>>(zA, P, cv_g + HH, cv_be + HH,
                                  lin1_w, lin1_b, lin2_w, lin2_b, nf,
                                  ep_w1, ep_b1, Ah, Bh);

  k_edges_f16<<<EBLK, 256, 0, stream>>>(Ah, Bh, Wf, ep_b2, ep_b3, ep_b4, out);
  k_mirror<<<1176, 256, 0, stream>>>(out);
}